// Round 12
// baseline (129.701 us; speedup 1.0000x reference)
//
#include <hip/hip_runtime.h>
#include <hip/hip_bf16.h>

#define SS 2048
#define DD 128
#define BB 16
#define LDST 136  // xs staging pad (ushorts)
#define SCT 268   // sc stride (ushorts)

typedef short bf16x8 __attribute__((ext_vector_type(8)));
typedef float f32x4 __attribute__((ext_vector_type(4)));
typedef float f32x16 __attribute__((ext_vector_type(16)));
typedef unsigned short ushort_t;

#define SB0() __builtin_amdgcn_sched_barrier(0)
#define WAITV(n) asm volatile("s_waitcnt vmcnt(" #n ")" ::: "memory")

__device__ __forceinline__ unsigned short f2bf(float f) {
  union { float f; unsigned u; } v; v.f = f;
  unsigned r = v.u + 0x7fffu + ((v.u >> 16) & 1u);  // RNE
  return (unsigned short)(r >> 16);
}
__device__ __forceinline__ float fexp2(float x) { return __builtin_amdgcn_exp2f(x); }

// NEW frag-major layout for 32x32x16 MFMA:
// chunk index ((H*8 + w)*64 + lane), 16 B each. H = 32-row group
// (64 per batch), w = 16-wide k(u) window. Lane l holds row H*32+(l&31),
// u = w*16 + (l>>5)*8 .. +8. This is exactly the A/B operand layout of
// mfma_f32_32x32x16_bf16 (row = l%32, k-slice = l/32), so one coalesced
// dwordx4 per (H,w) loads a full fragment.

// ---------------------------------------------------------------------------
// wprep: wt_g = [Wq^T * log2e/sqrt(U) ; Wk^T] bf16 [256][128].
// Coalesced LDS tile transpose (R11 version, verified).
// ---------------------------------------------------------------------------
__global__ __launch_bounds__(256) void wprep(
    const float* __restrict__ Wq, const float* __restrict__ Wk,
    ushort_t* __restrict__ wt_g) {
  const int isK = blockIdx.x >> 2, ut = (blockIdx.x >> 1) & 1, dt = blockIdx.x & 1;
  const int tid = threadIdx.x;
  const float* W = isK ? Wk : Wq;
  const float scale = isK ? 1.0f : 0.1275174346f;  // log2e/sqrt(128)
  __shared__ float tile[64][65];
  {
    int uu = tid & 63, dr = tid >> 6;
#pragma unroll
    for (int p = 0; p < 16; ++p) {
      int d = p * 4 + dr;
      tile[uu][d] = W[(size_t)(dt * 64 + d) * 128 + ut * 64 + uu];
    }
  }
  __syncthreads();
  {
    int d = tid & 63, ur = tid >> 6;
#pragma unroll
    for (int p = 0; p < 16; ++p) {
      int uu = p * 4 + ur;
      wt_g[(size_t)(isK * 128 + ut * 64 + uu) * 128 + dt * 64 + d] =
          f2bf(tile[uu][d] * scale);
    }
  }
}

// ---------------------------------------------------------------------------
// qk_gemm: [q|k] = bf16(x) @ wt_g^T. grid 512 (64 rows/block), block 256.
// Internals unchanged (R0-proven); ONLY the epilogue emits the new
// 32-row-group frag-major layout (free: it re-reads through sc LDS).
// ---------------------------------------------------------------------------
__global__ __launch_bounds__(256, 2) void qk_gemm(
    const float* __restrict__ x, const ushort_t* __restrict__ wt_g,
    uint4* __restrict__ qF, uint4* __restrict__ kF) {
  __shared__ ushort_t xs[64 * LDST];
  __shared__ ushort_t sc[64 * SCT];
  const int tid = threadIdx.x, wave = tid >> 6, lane = tid & 63;
  const int lq = lane & 15, quad = lane >> 4;
  const int m0 = blockIdx.x * 64;

#pragma unroll
  for (int i = 0; i < 8; ++i) {  // stage x: 64x128 fp32 -> bf16
    int idx = i * 256 + tid;
    int row = idx >> 5, c4 = (idx & 31) * 4;
    const float4 v = *(const float4*)(x + (size_t)(m0 + row) * DD + c4);
    ushort4 h;
    h.x = f2bf(v.x); h.y = f2bf(v.y); h.z = f2bf(v.z); h.w = f2bf(v.w);
    *(ushort4*)(&xs[row * LDST + c4]) = h;
  }
  bf16x8 wf[4][4];  // wave's 64 output cols, K=128
#pragma unroll
  for (int nt = 0; nt < 4; ++nt)
#pragma unroll
    for (int ks = 0; ks < 4; ++ks)
      wf[nt][ks] = *(const bf16x8*)(wt_g + (wave * 64 + nt * 16 + lq) * 128 + ks * 32 + quad * 8);
  __syncthreads();

  f32x4 acc[4][4];
#pragma unroll
  for (int mt = 0; mt < 4; ++mt)
#pragma unroll
    for (int nt = 0; nt < 4; ++nt) acc[mt][nt] = (f32x4){0.f, 0.f, 0.f, 0.f};
#pragma unroll
  for (int mt = 0; mt < 4; ++mt) {
    bf16x8 af[4];
#pragma unroll
    for (int ks = 0; ks < 4; ++ks)
      af[ks] = *(const bf16x8*)(&xs[(mt * 16 + lq) * LDST + ks * 32 + quad * 8]);
#pragma unroll
    for (int nt = 0; nt < 4; ++nt)
#pragma unroll
      for (int ks = 0; ks < 4; ++ks)
        acc[mt][nt] = __builtin_amdgcn_mfma_f32_16x16x32_bf16(af[ks], wf[nt][ks], acc[mt][nt], 0, 0, 0);
  }
  // C/D 16x16: row = mt*16+quad*4+r, col = wave*64+nt*16+lq
#pragma unroll
  for (int mt = 0; mt < 4; ++mt)
#pragma unroll
    for (int nt = 0; nt < 4; ++nt)
#pragma unroll
      for (int r = 0; r < 4; ++r)
        sc[(mt * 16 + quad * 4 + r) * SCT + wave * 64 + nt * 16 + lq] = f2bf(acc[mt][nt][r]);
  __syncthreads();
  // epilogue: emit 32-row-group chunks. slot ci: isk(1b) Hloc(1b) w(3b).
#pragma unroll
  for (int i = 0; i < 8; ++i) {
    int c = i * 256 + tid;                 // 0..2047
    int lane_c = c & 63, ci = c >> 6;      // chunk slot 0..31
    int wv = ci & 7, Hloc = (ci >> 3) & 1, isk = ci >> 4;
    int row = Hloc * 32 + (lane_c & 31);
    int col = isk * 128 + wv * 16 + (lane_c >> 5) * 8;
    uint4 v = *(const uint4*)(&sc[row * SCT + col]);
    uint4* dst = isk ? kF : qF;
    dst[((size_t)(blockIdx.x * 2 + Hloc) * 8 + wv) * 64 + lane_c] = v;
  }
}

// ---------------------------------------------------------------------------
// attn_fused: R12 — 32x32x16 MFMA. Same FLOPs, HALF the MFMA and HALF the
// vector-mem instructions per wave (16 MFMA + 8 loads now cover a 32-j
// group vs 16 j before); 32x32 ubench rate is +15% over 16x16.
//
// grid 512 = XCD-chunked (b,ib); block 256 (4 waves); wave covers the
// block's 64 i-rows (2 row-groups) x 16 j-groups Hj = m*4+wave, 32 j each.
// Depth-2 counted-vmcnt pipeline kept from R8 (8 loads/group, WAITV(8)).
// C/D layout (verified m74/m101): col = lane&31,
// row = (r&3) + 8*(r>>2) + 4*(lane>>5), r in [0,16).
// Regs: af 64 + fA/fB 64 + acc 32 + rowsum|creg 32 + misc ~ 205 < 256.
// ---------------------------------------------------------------------------
__global__ __launch_bounds__(256, 2) void attn_fused(
    const uint4* __restrict__ qF, const uint4* __restrict__ kF,
    const float* __restrict__ t, const float* __restrict__ theta,
    const float* __restrict__ mu, float* __restrict__ w) {
  const int xcd = blockIdx.x & 7, s = blockIdx.x >> 3;  // wgid%8 -> XCD
  const int b = xcd + ((s >> 5) << 3);
  const int ib = s & 31;
  const int i0 = ib * 64;
  const int tid = threadIdx.x, wave = tid >> 6, lane = tid & 63;
  const int l31 = lane & 31, lh = lane >> 5;

  __shared__ float rs_lds[4][64];
  __shared__ float c_lds[64];

  const bf16x8* qc = (const bf16x8*)qF;
  bf16x8 af[2][8];  // 2 row-groups x 8 k-windows
#pragma unroll
  for (int ht = 0; ht < 2; ++ht)
#pragma unroll
    for (int wv = 0; wv < 8; ++wv)
      af[ht][wv] = qc[((size_t)(b * 64 + ib * 2 + ht) * 8 + wv) * 64 + lane];

  const bf16x8* kb = (const bf16x8*)kF + (size_t)b * 64 * 8 * 64 + lane;
  auto loadg = [&](bf16x8 (&f)[8], int hj) {
#pragma unroll
    for (int wv = 0; wv < 8; ++wv)
      f[wv] = kb[((size_t)hj * 8 + wv) * 64];
  };
  auto HJ = [&](int m) { return m * 4 + wave; };

  const f32x16 z16 = {0.f, 0.f, 0.f, 0.f, 0.f, 0.f, 0.f, 0.f,
                      0.f, 0.f, 0.f, 0.f, 0.f, 0.f, 0.f, 0.f};
  auto mfma32 = [&](f32x16 (&a)[2], bf16x8 (&f)[8]) {
    __builtin_amdgcn_s_setprio(1);
#pragma unroll
    for (int ht = 0; ht < 2; ++ht)
      a[ht] = __builtin_amdgcn_mfma_f32_32x32x16_bf16(af[ht][0], f[0], z16, 0, 0, 0);
#pragma unroll
    for (int wv = 1; wv < 8; ++wv)
#pragma unroll
      for (int ht = 0; ht < 2; ++ht)
        a[ht] = __builtin_amdgcn_mfma_f32_32x32x16_bf16(af[ht][wv], f[wv], a[ht], 0, 0, 0);
    __builtin_amdgcn_s_setprio(0);
  };

  float rowsum[2][16];
#pragma unroll
  for (int ht = 0; ht < 2; ++ht)
#pragma unroll
    for (int r = 0; r < 16; ++r) rowsum[ht][r] = 0.f;
  auto proc1 = [&](f32x16 (&a)[2]) {
#pragma unroll
    for (int ht = 0; ht < 2; ++ht)
#pragma unroll
      for (int r = 0; r < 16; ++r) rowsum[ht][r] += fexp2(a[ht][r]);
  };

  bf16x8 fA[8], fB[8];
  f32x16 a[2];

  // ---- PASS 1: row sums (depth-2 counted-vmcnt, 16 j-groups/wave) ----
  loadg(fA, HJ(0));
  loadg(fB, HJ(1));                      // 16 loads in flight
  for (int m = 0; m < 14; m += 2) {
    WAITV(8); SB0();                     // fA landed
    mfma32(a, fA);
    loadg(fA, HJ(m + 2)); SB0();
    proc1(a);
    WAITV(8); SB0();                     // fB landed
    mfma32(a, fB);
    loadg(fB, HJ(m + 3)); SB0();
    proc1(a);
  }
  WAITV(8); SB0(); mfma32(a, fA); SB0(); proc1(a);
  WAITV(0); SB0(); mfma32(a, fB); SB0(); proc1(a);

  // reduce over 32 j-cols (lanes within each half hold distinct cols)
#pragma unroll
  for (int d2 = 1; d2 <= 16; d2 <<= 1)
#pragma unroll
    for (int ht = 0; ht < 2; ++ht)
#pragma unroll
      for (int r = 0; r < 16; ++r)
        rowsum[ht][r] += __shfl_xor(rowsum[ht][r], d2, 64);
  if (l31 == 0) {  // lanes 0 and 32: each owns 32 of the 64 local rows
#pragma unroll
    for (int ht = 0; ht < 2; ++ht)
#pragma unroll
      for (int r = 0; r < 16; ++r)
        rs_lds[wave][ht * 32 + (r & 3) + 8 * (r >> 2) + 4 * lh] = rowsum[ht][r];
  }
  __syncthreads();
  if (tid < 64) {
    float l = rs_lds[0][tid] + rs_lds[1][tid] + rs_lds[2][tid] + rs_lds[3][tid];
    int gi = i0 + tid;
    float z = theta[gi] - mu[gi] * t[b * SS + gi];
    float tf = 1.f / (1.f + fexp2(-z * 1.44269504f));
    c_lds[tid] = tf / l;
  }
  __syncthreads();
  float creg[2][16];
#pragma unroll
  for (int ht = 0; ht < 2; ++ht)
#pragma unroll
    for (int r = 0; r < 16; ++r)
      creg[ht][r] = c_lds[ht * 32 + (r & 3) + 8 * (r >> 2) + 4 * lh];

  auto proc2 = [&](f32x16 (&aa)[2], int hj) {
    float c0 = 0.f, c1 = 0.f;
#pragma unroll
    for (int r = 0; r < 16; ++r) {
      c0 = fmaf(creg[0][r], fexp2(aa[0][r]), c0);
      c1 = fmaf(creg[1][r], fexp2(aa[1][r]), c1);
    }
    float cs = c0 + c1;
    cs += __shfl_xor(cs, 32, 64);        // join the two row-halves
    if (lane < 32) atomicAdd(&w[b * SS + hj * 32 + l31], cs);
  };

  // ---- PASS 2: column sums -> w ----
  loadg(fA, HJ(0));
  loadg(fB, HJ(1));
  for (int m = 0; m < 14; m += 2) {
    WAITV(8); SB0();
    mfma32(a, fA);
    loadg(fA, HJ(m + 2)); SB0();
    proc2(a, HJ(m));
    WAITV(8); SB0();
    mfma32(a, fB);
    loadg(fB, HJ(m + 3)); SB0();
    proc2(a, HJ(m + 1));
  }
  WAITV(8); SB0(); mfma32(a, fA); SB0(); proc2(a, HJ(14));
  WAITV(0); SB0(); mfma32(a, fB); SB0(); proc2(a, HJ(15));
}

// ---------------------------------------------------------------------------
// finalize: v[b,d] = sum_j w[b,j] * x[b,j,d].  grid 512. (R8 version)
// ---------------------------------------------------------------------------
__global__ __launch_bounds__(256) void finalize(
    const float* __restrict__ x, const float* __restrict__ w,
    float* __restrict__ out) {
  const int b = blockIdx.x >> 5;
  const int j0 = (blockIdx.x & 31) * 64;
  const int tid = threadIdx.x;
  const int d4 = (tid & 31) * 4, jo = tid >> 5;  // 32 d-groups x 8 j-offsets
  float4 a0 = {0.f, 0.f, 0.f, 0.f}, a1 = {0.f, 0.f, 0.f, 0.f};
#pragma unroll
  for (int jj = 0; jj < 4; ++jj) {
    int ja = j0 + jj * 16 + jo, jb = ja + 8;
    float wa = w[b * SS + ja], wb = w[b * SS + jb];
    const float4 xa = *(const float4*)(x + ((size_t)b * SS + ja) * DD + d4);
    const float4 xb = *(const float4*)(x + ((size_t)b * SS + jb) * DD + d4);
    a0.x = fmaf(wa, xa.x, a0.x); a0.y = fmaf(wa, xa.y, a0.y);
    a0.z = fmaf(wa, xa.z, a0.z); a0.w = fmaf(wa, xa.w, a0.w);
    a1.x = fmaf(wb, xb.x, a1.x); a1.y = fmaf(wb, xb.y, a1.y);
    a1.z = fmaf(wb, xb.z, a1.z); a1.w = fmaf(wb, xb.w, a1.w);
  }
  __shared__ float4 red[256];
  float4 acc = {a0.x + a1.x, a0.y + a1.y, a0.z + a1.z, a0.w + a1.w};
  red[tid] = acc;
  __syncthreads();
  if (tid < 128) {
    float4 o = red[tid + 128];
    red[tid].x += o.x; red[tid].y += o.y; red[tid].z += o.z; red[tid].w += o.w;
  }
  __syncthreads();
  if (tid < 64) {
    float4 o = red[tid + 64];
    red[tid].x += o.x; red[tid].y += o.y; red[tid].z += o.z; red[tid].w += o.w;
  }
  __syncthreads();
  if (tid < 32) {
    float4 v = red[tid], o = red[tid + 32];
    v.x += o.x; v.y += o.y; v.z += o.z; v.w += o.w;
    atomicAdd(&out[b * DD + d4 + 0], v.x);
    atomicAdd(&out[b * DD + d4 + 1], v.y);
    atomicAdd(&out[b * DD + d4 + 2], v.z);
    atomicAdd(&out[b * DD + d4 + 3], v.w);
  }
}

extern "C" void kernel_launch(void* const* d_in, const int* in_sizes, int n_in,
                              void* d_out, int out_size, void* d_ws, size_t ws_size,
                              hipStream_t stream) {
  const float* x = (const float*)d_in[0];
  const float* t = (const float*)d_in[1];
  const float* Wq = (const float*)d_in[2];
  const float* Wk = (const float*)d_in[3];
  const float* theta = (const float*)d_in[4];
  const float* mu = (const float*)d_in[5];
  float* out = (float*)d_out;

  uint4* qF = (uint4*)d_ws;                             // 8.4 MB (frag-major 32-row groups)
  uint4* kF = qF + (size_t)16 * 64 * 8 * 64;            // 8.4 MB
  ushort_t* wt_g = (ushort_t*)(kF + (size_t)16 * 64 * 8 * 64);  // 64 KB
  float* w = (float*)(wt_g + 256 * 128);                // 128 KB

  hipMemsetAsync(w, 0, (size_t)BB * SS * sizeof(float), stream);
  hipMemsetAsync(d_out, 0, (size_t)BB * DD * sizeof(float), stream);

  wprep<<<dim3(8), dim3(256), 0, stream>>>(Wq, Wk, wt_g);
  qk_gemm<<<dim3(512), dim3(256), 0, stream>>>(x, wt_g, qF, kF);
  attn_fused<<<dim3(512), dim3(256), 0, stream>>>(qF, kF, t, theta, mu, w);
  finalize<<<dim3(512), dim3(256), 0, stream>>>(x, w, out);
}

// Round 13
// 126.188 us; speedup vs baseline: 1.0278x; 1.0278x over previous
//
#include <hip/hip_runtime.h>
#include <hip/hip_bf16.h>

#define SS 2048
#define DD 128
#define BB 16
#define LDST 136  // xs staging pad (ushorts)
#define SCT 268   // sc stride: 4-way max on frag-order epilogue reads

typedef short bf16x8 __attribute__((ext_vector_type(8)));
typedef float f32x4 __attribute__((ext_vector_type(4)));
typedef unsigned short ushort_t;

#define SB0() __builtin_amdgcn_sched_barrier(0)
#define WAITV(n) asm volatile("s_waitcnt vmcnt(" #n ")" ::: "memory")

__device__ __forceinline__ unsigned short f2bf(float f) {
  union { float f; unsigned u; } v; v.f = f;
  unsigned r = v.u + 0x7fffu + ((v.u >> 16) & 1u);  // RNE
  return (unsigned short)(r >> 16);
}
__device__ __forceinline__ float fexp2(float x) { return __builtin_amdgcn_exp2f(x); }

// Fragment-major layout: chunk index ((G*4 + ks)*64 + lane), 16 B each.
// G = global 16-row group (b*128 + g), lane = quad*16 + lq holds
// rows[G*16+lq], cols[ks*32+quad*8 .. +8].
//
// SESSION SUMMARY (12 rounds): attn_fused is pinned at ~42.6 us = 808 TF
// effective (the plain-HIP streaming-MFMA band). Falsified as limiters:
// occupancy (R4), HBM traffic (R8: FETCH 70->8.4 MB, no change), L2
// bytes (R9 L1-share), LDS staging (R7: -45%), pipeline depth/structure
// (R1/R8), SGB interleave (R10), MFMA shape/instr count (R12). ~85 us of
// the 127 us total is fixed harness cost (256 MB workspace re-poison +
// reset dispatches). This file is the measured session minimum (R8).

// ---------------------------------------------------------------------------
// wprep: wt_g = [Wq^T * log2e/sqrt(U) ; Wk^T] bf16 [256][128]. grid 128.
// ---------------------------------------------------------------------------
__global__ __launch_bounds__(256) void wprep(
    const float* __restrict__ Wq, const float* __restrict__ Wk,
    ushort_t* __restrict__ wt_g) {
  int idx = blockIdx.x * 256 + threadIdx.x;  // 0..32767
  int r = idx & 16383, uu = r >> 7, d = r & 127;
  if (idx < 16384)
    wt_g[uu * 128 + d] = f2bf(Wq[d * 128 + uu] * 0.1275174346f);  // log2e/sqrt(128)
  else
    wt_g[(uu + 128) * 128 + d] = f2bf(Wk[d * 128 + uu]);
}

// ---------------------------------------------------------------------------
// qk_gemm: [q|k] = bf16(x) @ wt_g^T, output in FRAG-MAJOR layout.
// grid 512 (64 rows/block), block 256.
// ---------------------------------------------------------------------------
__global__ __launch_bounds__(256, 2) void qk_gemm(
    const float* __restrict__ x, const ushort_t* __restrict__ wt_g,
    uint4* __restrict__ qF, uint4* __restrict__ kF) {
  __shared__ ushort_t xs[64 * LDST];
  __shared__ ushort_t sc[64 * SCT];
  const int tid = threadIdx.x, wave = tid >> 6, lane = tid & 63;
  const int lq = lane & 15, quad = lane >> 4;
  const int m0 = blockIdx.x * 64;

#pragma unroll
  for (int i = 0; i < 8; ++i) {  // stage x: 64x128 fp32 -> bf16
    int idx = i * 256 + tid;
    int row = idx >> 5, c4 = (idx & 31) * 4;
    const float4 v = *(const float4*)(x + (size_t)(m0 + row) * DD + c4);
    ushort4 h;
    h.x = f2bf(v.x); h.y = f2bf(v.y); h.z = f2bf(v.z); h.w = f2bf(v.w);
    *(ushort4*)(&xs[row * LDST + c4]) = h;
  }
  bf16x8 wf[4][4];  // wave's 64 output cols, K=128
#pragma unroll
  for (int nt = 0; nt < 4; ++nt)
#pragma unroll
    for (int ks = 0; ks < 4; ++ks)
      wf[nt][ks] = *(const bf16x8*)(wt_g + (wave * 64 + nt * 16 + lq) * 128 + ks * 32 + quad * 8);
  __syncthreads();

  f32x4 acc[4][4];
#pragma unroll
  for (int mt = 0; mt < 4; ++mt)
#pragma unroll
    for (int nt = 0; nt < 4; ++nt) acc[mt][nt] = (f32x4){0.f, 0.f, 0.f, 0.f};
#pragma unroll
  for (int mt = 0; mt < 4; ++mt) {
    bf16x8 af[4];
#pragma unroll
    for (int ks = 0; ks < 4; ++ks)
      af[ks] = *(const bf16x8*)(&xs[(mt * 16 + lq) * LDST + ks * 32 + quad * 8]);
#pragma unroll
    for (int nt = 0; nt < 4; ++nt)
#pragma unroll
      for (int ks = 0; ks < 4; ++ks)
        acc[mt][nt] = __builtin_amdgcn_mfma_f32_16x16x32_bf16(af[ks], wf[nt][ks], acc[mt][nt], 0, 0, 0);
  }
#pragma unroll
  for (int mt = 0; mt < 4; ++mt)
#pragma unroll
    for (int nt = 0; nt < 4; ++nt)
#pragma unroll
      for (int r = 0; r < 4; ++r)
        sc[(mt * 16 + quad * 4 + r) * SCT + wave * 64 + nt * 16 + lq] = f2bf(acc[mt][nt][r]);
  __syncthreads();
#pragma unroll
  for (int i = 0; i < 8; ++i) {
    int c = i * 256 + tid;                 // 0..2047
    int lane_c = c & 63, ks_c = (c >> 6) & 3, g_c = (c >> 8) & 3, isk = c >> 10;
    int li = lane_c & 15, qd = lane_c >> 4;
    int col = isk * 128 + ks_c * 32 + qd * 8;
    uint4 v = *(const uint4*)(&sc[(g_c * 16 + li) * SCT + col]);
    size_t G = (size_t)blockIdx.x * 4 + g_c;
    uint4* dst = isk ? kF : qF;
    dst[(G * 4 + ks_c) * 64 + lane_c] = v;
  }
}

// ---------------------------------------------------------------------------
// attn_fused: both passes, direct frag-major loads, XCD-chunked dispatch
// (K/Q stream fully L2-resident: FETCH 8.4 MB), depth-2 counted-vmcnt
// pipeline (never drains mid-loop). Session-best form: 42.6 us, VGPR 76.
// ---------------------------------------------------------------------------
__global__ __launch_bounds__(256, 2) void attn_fused(
    const uint4* __restrict__ qF, const uint4* __restrict__ kF,
    const float* __restrict__ t, const float* __restrict__ theta,
    const float* __restrict__ mu, float* __restrict__ w) {
  const int xcd = blockIdx.x & 7, s = blockIdx.x >> 3;  // wgid%8 -> XCD
  const int b = xcd + ((s >> 5) << 3);
  const int ib = s & 31;
  const int i0 = ib * 64;
  const int tid = threadIdx.x, wave = tid >> 6, lane = tid & 63;
  const int lq = lane & 15, quad = lane >> 4;

  __shared__ float rs_lds[4][64];
  __shared__ float c_lds[64];

  const bf16x8* qc = (const bf16x8*)qF;
  bf16x8 af[4][4];
#pragma unroll
  for (int mt = 0; mt < 4; ++mt)
#pragma unroll
    for (int ks = 0; ks < 4; ++ks)
      af[mt][ks] = qc[((size_t)(b * 128 + ib * 4 + mt) * 4 + ks) * 64 + lane];

  const bf16x8* kb = (const bf16x8*)kF + (size_t)b * 128 * 4 * 64 + lane;
  auto loadg = [&](bf16x8 (&f)[4], int g) {
#pragma unroll
    for (int ks = 0; ks < 4; ++ks)
      f[ks] = kb[((size_t)g * 4 + ks) * 64];
  };
  auto G = [&](int m) { return (m >> 1) * 8 + wave * 2 + (m & 1); };

  const f32x4 z4 = {0.f, 0.f, 0.f, 0.f};
  auto mfma16 = [&](f32x4 (&a)[4], bf16x8 (&f)[4]) {
    __builtin_amdgcn_s_setprio(1);
#pragma unroll
    for (int mt = 0; mt < 4; ++mt)
      a[mt] = __builtin_amdgcn_mfma_f32_16x16x32_bf16(af[mt][0], f[0], z4, 0, 0, 0);
#pragma unroll
    for (int ks = 1; ks < 4; ++ks)
#pragma unroll
      for (int mt = 0; mt < 4; ++mt)
        a[mt] = __builtin_amdgcn_mfma_f32_16x16x32_bf16(af[mt][ks], f[ks], a[mt], 0, 0, 0);
    __builtin_amdgcn_s_setprio(0);
  };

  float rowsum[4][4];
#pragma unroll
  for (int mt = 0; mt < 4; ++mt)
#pragma unroll
    for (int r = 0; r < 4; ++r) rowsum[mt][r] = 0.f;
  auto proc1 = [&](f32x4 (&a)[4]) {
#pragma unroll
    for (int mt = 0; mt < 4; ++mt)
#pragma unroll
      for (int r = 0; r < 4; ++r) rowsum[mt][r] += fexp2(a[mt][r]);
  };

  bf16x8 fA[4], fB[4];
  f32x4 a[4];

  // ---- PASS 1: row sums (depth-2 counted-vmcnt pipeline) ----
  loadg(fA, G(0));
  loadg(fB, G(1));                       // 8 loads in flight
  for (int m = 0; m < 30; m += 2) {
    WAITV(4); SB0();                     // oldest 4 (fA) landed
    mfma16(a, fA);
    loadg(fA, G(m + 2)); SB0();          // refill while exp2 runs
    proc1(a);
    WAITV(4); SB0();
    mfma16(a, fB);
    loadg(fB, G(m + 3)); SB0();
    proc1(a);
  }
  WAITV(4); SB0(); mfma16(a, fA); SB0(); proc1(a);
  WAITV(0); SB0(); mfma16(a, fB); SB0(); proc1(a);

#pragma unroll
  for (int d2 = 1; d2 <= 8; d2 <<= 1)
#pragma unroll
    for (int mt = 0; mt < 4; ++mt)
#pragma unroll
      for (int r = 0; r < 4; ++r)
        rowsum[mt][r] += __shfl_xor(rowsum[mt][r], d2, 64);
  if (lq == 0) {
#pragma unroll
    for (int mt = 0; mt < 4; ++mt)
#pragma unroll
      for (int r = 0; r < 4; ++r)
        rs_lds[wave][mt * 16 + quad * 4 + r] = rowsum[mt][r];
  }
  __syncthreads();
  if (tid < 64) {
    float l = rs_lds[0][tid] + rs_lds[1][tid] + rs_lds[2][tid] + rs_lds[3][tid];
    int gi = i0 + tid;
    float z = theta[gi] - mu[gi] * t[b * SS + gi];
    float tf = 1.f / (1.f + fexp2(-z * 1.44269504f));
    c_lds[tid] = tf / l;
  }
  __syncthreads();
  float creg[4][4];
#pragma unroll
  for (int mt = 0; mt < 4; ++mt)
#pragma unroll
    for (int r = 0; r < 4; ++r) creg[mt][r] = c_lds[mt * 16 + quad * 4 + r];

  auto proc2 = [&](f32x4 (&aa)[4], int g) {
    float cs = 0.f;
#pragma unroll
    for (int mt = 0; mt < 4; ++mt)
#pragma unroll
      for (int r = 0; r < 4; ++r) cs = fmaf(creg[mt][r], fexp2(aa[mt][r]), cs);
    cs += __shfl_xor(cs, 16, 64);
    cs += __shfl_xor(cs, 32, 64);
    if (lane < 16) atomicAdd(&w[b * SS + g * 16 + lane], cs);
  };

  // ---- PASS 2: column sums -> w (same pipeline; af reused) ----
  loadg(fA, G(0));
  loadg(fB, G(1));
  for (int m = 0; m < 30; m += 2) {
    WAITV(4); SB0();
    mfma16(a, fA);
    loadg(fA, G(m + 2)); SB0();
    proc2(a, G(m));
    WAITV(4); SB0();
    mfma16(a, fB);
    loadg(fB, G(m + 3)); SB0();
    proc2(a, G(m + 1));
  }
  WAITV(4); SB0(); mfma16(a, fA); SB0(); proc2(a, G(30));
  WAITV(0); SB0(); mfma16(a, fB); SB0(); proc2(a, G(31));
}

// ---------------------------------------------------------------------------
// finalize: v[b,d] = sum_j w[b,j] * x[b,j,d].  grid 512 (64 j per block).
// Vectorized: float4 x loads, 2 independent accumulators, tree reduce.
// ---------------------------------------------------------------------------
__global__ __launch_bounds__(256) void finalize(
    const float* __restrict__ x, const float* __restrict__ w,
    float* __restrict__ out) {
  const int b = blockIdx.x >> 5;
  const int j0 = (blockIdx.x & 31) * 64;
  const int tid = threadIdx.x;
  const int d4 = (tid & 31) * 4, jo = tid >> 5;  // 32 d-groups x 8 j-offsets
  float4 a0 = {0.f, 0.f, 0.f, 0.f}, a1 = {0.f, 0.f, 0.f, 0.f};
#pragma unroll
  for (int jj = 0; jj < 4; ++jj) {
    int ja = j0 + jj * 16 + jo, jb = ja + 8;
    float wa = w[b * SS + ja], wb = w[b * SS + jb];
    const float4 xa = *(const float4*)(x + ((size_t)b * SS + ja) * DD + d4);
    const float4 xb = *(const float4*)(x + ((size_t)b * SS + jb) * DD + d4);
    a0.x = fmaf(wa, xa.x, a0.x); a0.y = fmaf(wa, xa.y, a0.y);
    a0.z = fmaf(wa, xa.z, a0.z); a0.w = fmaf(wa, xa.w, a0.w);
    a1.x = fmaf(wb, xb.x, a1.x); a1.y = fmaf(wb, xb.y, a1.y);
    a1.z = fmaf(wb, xb.z, a1.z); a1.w = fmaf(wb, xb.w, a1.w);
  }
  __shared__ float4 red[256];
  float4 acc = {a0.x + a1.x, a0.y + a1.y, a0.z + a1.z, a0.w + a1.w};
  red[tid] = acc;
  __syncthreads();
  if (tid < 128) {
    float4 o = red[tid + 128];
    red[tid].x += o.x; red[tid].y += o.y; red[tid].z += o.z; red[tid].w += o.w;
  }
  __syncthreads();
  if (tid < 64) {
    float4 o = red[tid + 64];
    red[tid].x += o.x; red[tid].y += o.y; red[tid].z += o.z; red[tid].w += o.w;
  }
  __syncthreads();
  if (tid < 32) {
    float4 v = red[tid], o = red[tid + 32];
    v.x += o.x; v.y += o.y; v.z += o.z; v.w += o.w;
    atomicAdd(&out[b * DD + d4 + 0], v.x);
    atomicAdd(&out[b * DD + d4 + 1], v.y);
    atomicAdd(&out[b * DD + d4 + 2], v.z);
    atomicAdd(&out[b * DD + d4 + 3], v.w);
  }
}

extern "C" void kernel_launch(void* const* d_in, const int* in_sizes, int n_in,
                              void* d_out, int out_size, void* d_ws, size_t ws_size,
                              hipStream_t stream) {
  const float* x = (const float*)d_in[0];
  const float* t = (const float*)d_in[1];
  const float* Wq = (const float*)d_in[2];
  const float* Wk = (const float*)d_in[3];
  const float* theta = (const float*)d_in[4];
  const float* mu = (const float*)d_in[5];
  float* out = (float*)d_out;

  uint4* qF = (uint4*)d_ws;                             // 8.4 MB (frag-major)
  uint4* kF = qF + (size_t)2048 * 4 * 64;               // 8.4 MB (frag-major)
  ushort_t* wt_g = (ushort_t*)(kF + (size_t)2048 * 4 * 64);  // 64 KB
  float* w = (float*)(wt_g + 256 * 128);                // 128 KB

  hipMemsetAsync(w, 0, (size_t)BB * SS * sizeof(float), stream);
  hipMemsetAsync(d_out, 0, (size_t)BB * DD * sizeof(float), stream);

  wprep<<<dim3(128), dim3(256), 0, stream>>>(Wq, Wk, wt_g);
  qk_gemm<<<dim3(512), dim3(256), 0, stream>>>(x, wt_g, qF, kF);
  attn_fused<<<dim3(512), dim3(256), 0, stream>>>(qF, kF, t, theta, mu, w);
  finalize<<<dim3(512), dim3(256), 0, stream>>>(x, w, out);
}